// Round 6
// baseline (345.855 us; speedup 1.0000x reference)
//
#include <hip/hip_runtime.h>
#include <math.h>

// B=16, H=12, S=1024, D=64.  BH=192, rows = B*H*S = 196608.
// ws layout (bf16): Q[NE] | K[NE] | Vt[NE] | Wo_bf16[4096]

typedef __bf16 bf16x8 __attribute__((ext_vector_type(8)));
typedef float  f32x4  __attribute__((ext_vector_type(4)));

#define MFMA(a, b, c) __builtin_amdgcn_mfma_f32_16x16x32_bf16((a), (b), (c), 0, 0, 0)

static constexpr int S = 1024;
static constexpr int PAD = 72;      // 144 B row stride: 16B-aligned (b128-legal), breaks 128B aliasing
static constexpr size_t NE = 196608ull * 64ull;
// Q prescale: 1/sqrt(64) * log2(e)  -> scores arrive pre-scaled for exp2
static constexpr float QSCALE = 0.125f * 1.4426950408889634f;

__device__ inline unsigned long long pack4bf(float a, float b, float c, float d) {
    union { __bf16 h[4]; unsigned long long u; } pk;
    pk.h[0] = (__bf16)a; pk.h[1] = (__bf16)b; pk.h[2] = (__bf16)c; pk.h[3] = (__bf16)d;
    return pk.u;
}

// ---------------------------------------------------------------------------
// Kernel 0: Wo fp32 -> bf16 (consumed by attn's fused output projection)
// ---------------------------------------------------------------------------
__global__ void wo_conv(const float* __restrict__ Wo, __bf16* __restrict__ wob) {
    int i = (blockIdx.x * 256 + threadIdx.x) * 4;
    float4 v = *(const float4*)(Wo + i);
    *(unsigned long long*)(wob + i) = pack4bf(v.x, v.y, v.z, v.w);
}

// ---------------------------------------------------------------------------
// Kernel 1: Q/K/V projection, 128 rows/block, coalesced stores via LDS roundtrip.
// (~20-25 us incl. x fp32 read — not the bottleneck; unchanged from r5)
// ---------------------------------------------------------------------------
__global__ __launch_bounds__(256) void proj_qkv(
    const float* __restrict__ x,
    const float* __restrict__ Wq, const float* __restrict__ bq,
    const float* __restrict__ Wk, const float* __restrict__ bk,
    const float* __restrict__ Wv, const float* __restrict__ bv,
    __bf16* __restrict__ gq, __bf16* __restrict__ gk, __bf16* __restrict__ gvt)
{
    __shared__ __align__(16) __bf16 lx[128][PAD];
    __shared__ __align__(16) __bf16 lw[3][64][PAD];
    __shared__ __align__(16) __bf16 lbuf[128][PAD];   // roundtrip; reused as [64][136] for Vt
    __shared__ float lb[3][64];

    const int tid = threadIdx.x;
    const int row_base = blockIdx.x * 128;

    #pragma unroll
    for (int i = tid * 4; i < 8192; i += 1024) {
        float4 v = *(const float4*)(x + (size_t)row_base * 64 + i);
        int r = i >> 6, c = i & 63;
        *(unsigned long long*)&lx[r][c] = pack4bf(v.x, v.y, v.z, v.w);
    }
    const float* Ws[3] = {Wq, Wk, Wv};
    #pragma unroll
    for (int mtx = 0; mtx < 3; mtx++) {
        #pragma unroll
        for (int i = tid * 4; i < 4096; i += 1024) {
            float4 v = *(const float4*)(Ws[mtx] + i);
            int r = i >> 6, c = i & 63;
            *(unsigned long long*)&lw[mtx][r][c] = pack4bf(v.x, v.y, v.z, v.w);
        }
    }
    if (tid < 64) { lb[0][tid] = bq[tid]; lb[1][tid] = bk[tid]; lb[2][tid] = bv[tid]; }
    __syncthreads();

    const int w = tid >> 6, lane = tid & 63, m = lane & 15, quad = lane >> 4;
    const int bh = row_base >> 10;
    const int s_base = row_base & 1023;

    bf16x8 xf[2][2];
    #pragma unroll
    for (int g = 0; g < 2; g++) {
        xf[g][0] = *(const bf16x8*)&lx[w * 32 + g * 16 + m][quad * 8];
        xf[g][1] = *(const bf16x8*)&lx[w * 32 + g * 16 + m][32 + quad * 8];
    }

    #pragma unroll
    for (int mtx = 0; mtx < 2; mtx++) {
        #pragma unroll
        for (int et = 0; et < 4; et++) {
            bf16x8 wf0 = *(const bf16x8*)&lw[mtx][et * 16 + m][quad * 8];
            bf16x8 wf1 = *(const bf16x8*)&lw[mtx][et * 16 + m][32 + quad * 8];
            float4 bias = *(const float4*)&lb[mtx][et * 16 + quad * 4];
            #pragma unroll
            for (int g = 0; g < 2; g++) {
                f32x4 acc = {0.f, 0.f, 0.f, 0.f};
                acc = MFMA(wf0, xf[g][0], acc);
                acc = MFMA(wf1, xf[g][1], acc);
                unsigned long long u;
                if (mtx == 0)
                    u = pack4bf((acc[0] + bias.x) * QSCALE, (acc[1] + bias.y) * QSCALE,
                                (acc[2] + bias.z) * QSCALE, (acc[3] + bias.w) * QSCALE);
                else
                    u = pack4bf(acc[0] + bias.x, acc[1] + bias.y,
                                acc[2] + bias.z, acc[3] + bias.w);
                *(unsigned long long*)&lbuf[w * 32 + g * 16 + m][et * 16 + quad * 4] = u;
            }
        }
        __syncthreads();
        __bf16* dst = (mtx == 0 ? gq : gk);
        #pragma unroll
        for (int it = 0; it < 4; it++) {
            int idx = it * 256 + tid;
            int row = idx >> 3, col = (idx & 7) * 8;
            *(uint4*)(dst + ((size_t)row_base + row) * 64 + col) = *(uint4*)&lbuf[row][col];
        }
        __syncthreads();
    }

    __bf16 (*lvt)[136] = (__bf16(*)[136])&lbuf[0][0];
    #pragma unroll
    for (int et = 0; et < 4; et++) {
        bf16x8 wf0 = *(const bf16x8*)&lw[2][et * 16 + m][quad * 8];
        bf16x8 wf1 = *(const bf16x8*)&lw[2][et * 16 + m][32 + quad * 8];
        const float bias = lb[2][et * 16 + m];
        #pragma unroll
        for (int g = 0; g < 2; g++) {
            f32x4 acc = {0.f, 0.f, 0.f, 0.f};
            acc = MFMA(xf[g][0], wf0, acc);
            acc = MFMA(xf[g][1], wf1, acc);
            *(unsigned long long*)&lvt[et * 16 + m][w * 32 + g * 16 + quad * 4] =
                pack4bf(acc[0] + bias, acc[1] + bias, acc[2] + bias, acc[3] + bias);
        }
    }
    __syncthreads();
    #pragma unroll
    for (int it = 0; it < 4; it++) {
        int idx = it * 256 + tid;
        int row = idx >> 4, col = (idx & 15) * 8;
        *(uint4*)(gvt + ((size_t)bh * 64 + row) * 1024 + s_base + col) = *(uint4*)&lvt[row][col];
    }
}

// ---------------------------------------------------------------------------
// Kernel 2: flash attention + fused output projection — BARRIER-FREE.
// Block = 4 independent waves; each wave owns 64 q rows.  NO __syncthreads.
// K/V fragments loaded directly from global (L2-resident via XCD swizzle:
// grid (192 bh, 4 qb), same-bh blocks share linear-id%8 -> same XCD).
// Software pipeline: va(kb) issued before QK phase, ka(kb+1) before PV phase.
// LDS holds only the per-wave P/O roundtrip (36.9 KB -> 4 blocks/CU cap).
// __launch_bounds__(256,3): 3 waves/SIMD -> all 768 blocks resident, 1 round.
// ---------------------------------------------------------------------------
__global__ __launch_bounds__(256, 3) void attn(
    const __bf16* __restrict__ gq, const __bf16* __restrict__ gk,
    const __bf16* __restrict__ gvt, const __bf16* __restrict__ wob,
    const float* __restrict__ bo, float* __restrict__ out)
{
    __shared__ __align__(16) __bf16 lp[4][64][PAD];   // per-wave roundtrip [q][key] / [q][d]

    const int tid = threadIdx.x;
    const int w = tid >> 6, lane = tid & 63, m = lane & 15, quad = lane >> 4;
    const int bh = blockIdx.x;
    const int q0 = blockIdx.y * 256 + w * 64;

    const __bf16* kbase = gk + (size_t)bh * S * 64;
    const __bf16* vbase = gvt + (size_t)bh * 64 * 1024;

    // Q frags (B-operand), resident all kernel
    bf16x8 qf[4][2];
    #pragma unroll
    for (int g = 0; g < 4; g++) {
        const __bf16* qrow = gq + ((size_t)bh * S + q0 + g * 16 + m) * 64;
        qf[g][0] = *(const bf16x8*)(qrow + quad * 8);
        qf[g][1] = *(const bf16x8*)(qrow + 32 + quad * 8);
    }

    f32x4 o[4][4];
    float lsum[4] = {0.f, 0.f, 0.f, 0.f};
    #pragma unroll
    for (int g = 0; g < 4; g++)
        #pragma unroll
        for (int n = 0; n < 4; n++) o[g][n] = {0.f, 0.f, 0.f, 0.f};

    // preload K frags for kb=0 (A-operand: rows = keys t*16+m, k = d)
    bf16x8 ka[4][2];
    #pragma unroll
    for (int t = 0; t < 4; t++) {
        const __bf16* kr = kbase + (size_t)(t * 16 + m) * 64;
        ka[t][0] = *(const bf16x8*)(kr + quad * 8);
        ka[t][1] = *(const bf16x8*)(kr + 32 + quad * 8);
    }

    for (int kb = 0; kb < 16; kb++) {
        // V frags for THIS kb (A-operand: rows = d n*16+m, k = key) — in flight
        // during the QK/exp phase below.
        bf16x8 va[4][2];
        #pragma unroll
        for (int n = 0; n < 4; n++) {
            const __bf16* vr = vbase + (size_t)(n * 16 + m) * 1024 + kb * 64;
            va[n][0] = *(const bf16x8*)(vr + quad * 8);
            va[n][1] = *(const bf16x8*)(vr + 32 + quad * 8);
        }

        // QK: S^T tile -> exp2 -> lsum + packed P^T to per-wave LDS (single t pass)
        #pragma unroll
        for (int t = 0; t < 4; t++) {
            #pragma unroll
            for (int g = 0; g < 4; g++) {
                f32x4 acc = {0.f, 0.f, 0.f, 0.f};
                acc = MFMA(ka[t][0], qf[g][0], acc);
                acc = MFMA(ka[t][1], qf[g][1], acc);
                float e0 = __builtin_amdgcn_exp2f(acc[0]);
                float e1 = __builtin_amdgcn_exp2f(acc[1]);
                float e2 = __builtin_amdgcn_exp2f(acc[2]);
                float e3 = __builtin_amdgcn_exp2f(acc[3]);
                lsum[g] += (e0 + e1) + (e2 + e3);
                *(unsigned long long*)&lp[w][g * 16 + m][t * 16 + quad * 4] =
                    pack4bf(e0, e1, e2, e3);
            }
        }

        // P^T as B-operand (wave-private LDS, hw-ordered lgkmcnt — no barrier)
        bf16x8 pb[4][2];
        #pragma unroll
        for (int g = 0; g < 4; g++) {
            pb[g][0] = *(const bf16x8*)&lp[w][g * 16 + m][quad * 8];
            pb[g][1] = *(const bf16x8*)&lp[w][g * 16 + m][32 + quad * 8];
        }

        // prefetch K frags for kb+1 — in flight during the PV phase
        if (kb < 15) {
            #pragma unroll
            for (int t = 0; t < 4; t++) {
                const __bf16* kr = kbase + (size_t)((kb + 1) * 64 + t * 16 + m) * 64;
                ka[t][0] = *(const bf16x8*)(kr + quad * 8);
                ka[t][1] = *(const bf16x8*)(kr + 32 + quad * 8);
            }
        }

        // PV: O^T[d][q] += V^T[d][key] * P^T[key][q]
        #pragma unroll
        for (int n = 0; n < 4; n++) {
            #pragma unroll
            for (int g = 0; g < 4; g++) {
                o[g][n] = MFMA(va[n][0], pb[g][0], o[g][n]);
                o[g][n] = MFMA(va[n][1], pb[g][1], o[g][n]);
            }
        }
    }

    // ---- epilogue: l reduce, normalize O -> lp [q][d], fused @ Wo^T + bo ----
    #pragma unroll
    for (int g = 0; g < 4; g++) {
        lsum[g] += __shfl_xor(lsum[g], 16);
        lsum[g] += __shfl_xor(lsum[g], 32);
        const float inv = 1.f / lsum[g];
        #pragma unroll
        for (int n = 0; n < 4; n++) {
            *(unsigned long long*)&lp[w][g * 16 + m][n * 16 + quad * 4] =
                pack4bf(o[g][n][0] * inv, o[g][n][1] * inv,
                        o[g][n][2] * inv, o[g][n][3] * inv);
        }
    }

    bf16x8 wf[4][2];
    #pragma unroll
    for (int et = 0; et < 4; et++) {
        wf[et][0] = *(const bf16x8*)(wob + (size_t)(et * 16 + m) * 64 + quad * 8);
        wf[et][1] = *(const bf16x8*)(wob + (size_t)(et * 16 + m) * 64 + 32 + quad * 8);
    }
    float biasr[4];
    #pragma unroll
    for (int et = 0; et < 4; et++) biasr[et] = bo[et * 16 + m];

    #pragma unroll
    for (int g = 0; g < 4; g++) {
        bf16x8 af0 = *(const bf16x8*)&lp[w][g * 16 + m][quad * 8];
        bf16x8 af1 = *(const bf16x8*)&lp[w][g * 16 + m][32 + quad * 8];
        #pragma unroll
        for (int et = 0; et < 4; et++) {
            f32x4 acc = {0.f, 0.f, 0.f, 0.f};
            acc = MFMA(af0, wf[et][0], acc);
            acc = MFMA(af1, wf[et][1], acc);
            #pragma unroll
            for (int r = 0; r < 4; r++) {
                size_t row = (size_t)bh * S + q0 + g * 16 + quad * 4 + r;
                out[row * 64 + et * 16 + m] = acc[r] + biasr[et];
            }
        }
    }
}

// ---------------------------------------------------------------------------
extern "C" void kernel_launch(void* const* d_in, const int* in_sizes, int n_in,
                              void* d_out, int out_size, void* d_ws, size_t ws_size,
                              hipStream_t stream) {
    const float* x  = (const float*)d_in[0];
    const float* Wq = (const float*)d_in[1];
    const float* bq = (const float*)d_in[2];
    const float* Wk = (const float*)d_in[3];
    const float* bk = (const float*)d_in[4];
    const float* Wv = (const float*)d_in[5];
    const float* bv = (const float*)d_in[6];
    const float* Wo = (const float*)d_in[7];
    const float* bo = (const float*)d_in[8];
    float* out = (float*)d_out;

    __bf16* gq  = (__bf16*)d_ws;
    __bf16* gk  = gq + NE;
    __bf16* gvt = gk + NE;
    __bf16* wob = gvt + NE;

    wo_conv<<<4, 256, 0, stream>>>(Wo, wob);
    proj_qkv<<<1536, 256, 0, stream>>>(x, Wq, bq, Wk, bk, Wv, bv, gq, gk, gvt);
    attn<<<dim3(192, 4), 256, 0, stream>>>(gq, gk, gvt, wob, bo, out);
}

// Round 7
// 195.995 us; speedup vs baseline: 1.7646x; 1.7646x over previous
//
#include <hip/hip_runtime.h>
#include <math.h>

// B=16, H=12, S=1024, D=64.  BH=192, rows = B*H*S = 196608.
// ws layout (bf16): Q[NE] | K[NE] | Vt_perm[NE] | Wo_perm_bf16[4096]
//
// KEY-PERMUTATION TRICK: within each 64-key block, P^T exits QK in C-layout;
// reinterpreting those regs as a B-fragment supplies key kappa(s) at MFMA
// slot s, kappa(s) = 32*(s>>5) + 16*((s&7)>>2) + 4*((s&31)>>3) + (s&3).
// We store Vt (and Wo for the d-axis in the fused out-proj) pre-permuted by
// kappa, so P (and O) feed MFMA directly from registers — no LDS roundtrip.

typedef __bf16 bf16x8 __attribute__((ext_vector_type(8)));
typedef float  f32x4  __attribute__((ext_vector_type(4)));

#define MFMA(a, b, c) __builtin_amdgcn_mfma_f32_16x16x32_bf16((a), (b), (c), 0, 0, 0)

static constexpr int S = 1024;
static constexpr int PAD = 72;      // 144 B row stride: 16B-aligned (b128-legal), breaks 128B aliasing
static constexpr size_t NE = 196608ull * 64ull;
// Q prescale: 1/sqrt(64) * log2(e)  -> scores arrive pre-scaled for exp2
static constexpr float QSCALE = 0.125f * 1.4426950408889634f;

__device__ inline unsigned long long pack4bf(float a, float b, float c, float d) {
    union { __bf16 h[4]; unsigned long long u; } pk;
    pk.h[0] = (__bf16)a; pk.h[1] = (__bf16)b; pk.h[2] = (__bf16)c; pk.h[3] = (__bf16)d;
    return pk.u;
}

union frag_u { bf16x8 v; unsigned long long u[2]; };

// ---------------------------------------------------------------------------
// Kernel 0: Wo fp32 -> bf16, PERMUTED: wob[e][s] = Wo[e][kappa(s)].
// Groups of 4 consecutive s map to 4 consecutive d (kappa preserves s&3).
// ---------------------------------------------------------------------------
__global__ void wo_conv(const float* __restrict__ Wo, __bf16* __restrict__ wob) {
    int p = (blockIdx.x * 256 + threadIdx.x) * 4;   // output position, 4-aligned
    int e = p >> 6, s = p & 63;
    int h = s >> 5, qp = (s >> 3) & 3, tb = (s >> 2) & 1;
    int d0 = 32 * h + 16 * tb + 4 * qp;             // kappa(s) for s&3==0
    float4 v = *(const float4*)(Wo + e * 64 + d0);
    *(unsigned long long*)(wob + p) = pack4bf(v.x, v.y, v.z, v.w);
}

// ---------------------------------------------------------------------------
// Kernel 1: Q/K/V projection, 128 rows/block, coalesced stores via LDS roundtrip.
// Identical to r5 except the V-path writes into kappa-permuted positions
// (within each 64-key group; 4-key runs stay contiguous -> packed stores keep).
// ---------------------------------------------------------------------------
__global__ __launch_bounds__(256) void proj_qkv(
    const float* __restrict__ x,
    const float* __restrict__ Wq, const float* __restrict__ bq,
    const float* __restrict__ Wk, const float* __restrict__ bk,
    const float* __restrict__ Wv, const float* __restrict__ bv,
    __bf16* __restrict__ gq, __bf16* __restrict__ gk, __bf16* __restrict__ gvt)
{
    __shared__ __align__(16) __bf16 lx[128][PAD];
    __shared__ __align__(16) __bf16 lw[3][64][PAD];
    __shared__ __align__(16) __bf16 lbuf[128][PAD];   // roundtrip; reused as [64][136] for Vt
    __shared__ float lb[3][64];

    const int tid = threadIdx.x;
    const int row_base = blockIdx.x * 128;

    #pragma unroll
    for (int i = tid * 4; i < 8192; i += 1024) {
        float4 v = *(const float4*)(x + (size_t)row_base * 64 + i);
        int r = i >> 6, c = i & 63;
        *(unsigned long long*)&lx[r][c] = pack4bf(v.x, v.y, v.z, v.w);
    }
    const float* Ws[3] = {Wq, Wk, Wv};
    #pragma unroll
    for (int mtx = 0; mtx < 3; mtx++) {
        #pragma unroll
        for (int i = tid * 4; i < 4096; i += 1024) {
            float4 v = *(const float4*)(Ws[mtx] + i);
            int r = i >> 6, c = i & 63;
            *(unsigned long long*)&lw[mtx][r][c] = pack4bf(v.x, v.y, v.z, v.w);
        }
    }
    if (tid < 64) { lb[0][tid] = bq[tid]; lb[1][tid] = bk[tid]; lb[2][tid] = bv[tid]; }
    __syncthreads();

    const int w = tid >> 6, lane = tid & 63, m = lane & 15, quad = lane >> 4;
    const int bh = row_base >> 10;
    const int s_base = row_base & 1023;

    bf16x8 xf[2][2];
    #pragma unroll
    for (int g = 0; g < 2; g++) {
        xf[g][0] = *(const bf16x8*)&lx[w * 32 + g * 16 + m][quad * 8];
        xf[g][1] = *(const bf16x8*)&lx[w * 32 + g * 16 + m][32 + quad * 8];
    }

    #pragma unroll
    for (int mtx = 0; mtx < 2; mtx++) {
        #pragma unroll
        for (int et = 0; et < 4; et++) {
            bf16x8 wf0 = *(const bf16x8*)&lw[mtx][et * 16 + m][quad * 8];
            bf16x8 wf1 = *(const bf16x8*)&lw[mtx][et * 16 + m][32 + quad * 8];
            float4 bias = *(const float4*)&lb[mtx][et * 16 + quad * 4];
            #pragma unroll
            for (int g = 0; g < 2; g++) {
                f32x4 acc = {0.f, 0.f, 0.f, 0.f};
                acc = MFMA(wf0, xf[g][0], acc);
                acc = MFMA(wf1, xf[g][1], acc);
                unsigned long long u;
                if (mtx == 0)
                    u = pack4bf((acc[0] + bias.x) * QSCALE, (acc[1] + bias.y) * QSCALE,
                                (acc[2] + bias.z) * QSCALE, (acc[3] + bias.w) * QSCALE);
                else
                    u = pack4bf(acc[0] + bias.x, acc[1] + bias.y,
                                acc[2] + bias.z, acc[3] + bias.w);
                *(unsigned long long*)&lbuf[w * 32 + g * 16 + m][et * 16 + quad * 4] = u;
            }
        }
        __syncthreads();
        __bf16* dst = (mtx == 0 ? gq : gk);
        #pragma unroll
        for (int it = 0; it < 4; it++) {
            int idx = it * 256 + tid;
            int row = idx >> 3, col = (idx & 7) * 8;
            *(uint4*)(dst + ((size_t)row_base + row) * 64 + col) = *(uint4*)&lbuf[row][col];
        }
        __syncthreads();
    }

    // V path: rows s_local = w*32+g*16+quad*4+r, written to kappa-permuted pos.
    __bf16 (*lvt)[136] = (__bf16(*)[136])&lbuf[0][0];
    #pragma unroll
    for (int et = 0; et < 4; et++) {
        bf16x8 wf0 = *(const bf16x8*)&lw[2][et * 16 + m][quad * 8];
        bf16x8 wf1 = *(const bf16x8*)&lw[2][et * 16 + m][32 + quad * 8];
        const float bias = lb[2][et * 16 + m];
        #pragma unroll
        for (int g = 0; g < 2; g++) {
            f32x4 acc = {0.f, 0.f, 0.f, 0.f};
            acc = MFMA(xf[g][0], wf0, acc);
            acc = MFMA(xf[g][1], wf1, acc);
            // key group: group64 = w>>1, t' = (2w+g)&3, q' = quad
            const int tp = (2 * w + g) & 3;
            const int p0 = 64 * (w >> 1) + 32 * (tp >> 1) + 8 * quad + 4 * (tp & 1);
            *(unsigned long long*)&lvt[et * 16 + m][p0] =
                pack4bf(acc[0] + bias, acc[1] + bias, acc[2] + bias, acc[3] + bias);
        }
    }
    __syncthreads();
    #pragma unroll
    for (int it = 0; it < 4; it++) {
        int idx = it * 256 + tid;
        int row = idx >> 4, col = (idx & 15) * 8;
        *(uint4*)(gvt + ((size_t)bh * 64 + row) * 1024 + s_base + col) = *(uint4*)&lvt[row][col];
    }
}

// ---------------------------------------------------------------------------
// Kernel 2: flash attention + fused output projection.  r5 structure
// (2-barrier shared K/V staging, g-pairs) MINUS the lp roundtrip:
// P^T and O^T feed MFMA directly from registers (kappa-permuted Vt/Wo).
// LDS = lk + lv = 18.4 KB.  Grid (192 bh, 4 qb) -> same-bh same-XCD.
// ---------------------------------------------------------------------------
__global__ __launch_bounds__(256) void attn(
    const __bf16* __restrict__ gq, const __bf16* __restrict__ gk,
    const __bf16* __restrict__ gvt, const __bf16* __restrict__ wob,
    const float* __restrict__ bo, float* __restrict__ out)
{
    __shared__ __align__(16) __bf16 lk[64][PAD];        // K tile [key][d]
    __shared__ __align__(16) __bf16 lv[64][PAD];        // Vt tile [d][key-perm]

    const int tid = threadIdx.x;
    const int w = tid >> 6, lane = tid & 63, m = lane & 15, quad = lane >> 4;
    const int bh = blockIdx.x;
    const int q0 = blockIdx.y * 256 + w * 64;

    bf16x8 qf[4][2];
    #pragma unroll
    for (int g = 0; g < 4; g++) {
        const __bf16* qrow = gq + ((size_t)bh * S + q0 + g * 16 + m) * 64;
        qf[g][0] = *(const bf16x8*)(qrow + quad * 8);
        qf[g][1] = *(const bf16x8*)(qrow + 32 + quad * 8);
    }

    f32x4 o[4][4];
    float lsum[4] = {0.f, 0.f, 0.f, 0.f};
    #pragma unroll
    for (int g = 0; g < 4; g++)
        #pragma unroll
        for (int n = 0; n < 4; n++) o[g][n] = {0.f, 0.f, 0.f, 0.f};

    const int sr = tid >> 3;            // 0..31
    const int sc = (tid & 7) * 8;       // 16B chunk col
    const __bf16* kbase = gk + (size_t)bh * S * 64;
    const __bf16* vbase = gvt + (size_t)bh * 64 * 1024;

    uint4 kreg0 = *(const uint4*)(kbase + (size_t)sr * 64 + sc);
    uint4 kreg1 = *(const uint4*)(kbase + (size_t)(sr + 32) * 64 + sc);
    uint4 vreg0 = *(const uint4*)(vbase + (size_t)sr * 1024 + sc);
    uint4 vreg1 = *(const uint4*)(vbase + (size_t)(sr + 32) * 1024 + sc);

    for (int kb = 0; kb < 16; kb++) {
        __syncthreads();
        *(uint4*)&lk[sr][sc]      = kreg0;
        *(uint4*)&lk[sr + 32][sc] = kreg1;
        *(uint4*)&lv[sr][sc]      = vreg0;
        *(uint4*)&lv[sr + 32][sc] = vreg1;
        if (kb < 15) {
            const int nb = (kb + 1) * 64;
            kreg0 = *(const uint4*)(kbase + (size_t)(nb + sr) * 64 + sc);
            kreg1 = *(const uint4*)(kbase + (size_t)(nb + sr + 32) * 64 + sc);
            vreg0 = *(const uint4*)(vbase + (size_t)sr * 1024 + nb + sc);
            vreg1 = *(const uint4*)(vbase + (size_t)(sr + 32) * 1024 + nb + sc);
        }
        __syncthreads();

        #pragma unroll
        for (int gp = 0; gp < 2; gp++) {
            // QK -> exp2 -> pack P^T straight into B-fragments (no LDS)
            frag_u pb[2][2];
            #pragma unroll
            for (int t = 0; t < 4; t++) {
                bf16x8 ka0 = *(const bf16x8*)&lk[t * 16 + m][quad * 8];
                bf16x8 ka1 = *(const bf16x8*)&lk[t * 16 + m][32 + quad * 8];
                #pragma unroll
                for (int gl = 0; gl < 2; gl++) {
                    const int g = gp * 2 + gl;
                    f32x4 acc = {0.f, 0.f, 0.f, 0.f};
                    acc = MFMA(ka0, qf[g][0], acc);
                    acc = MFMA(ka1, qf[g][1], acc);
                    float e0 = __builtin_amdgcn_exp2f(acc[0]);
                    float e1 = __builtin_amdgcn_exp2f(acc[1]);
                    float e2 = __builtin_amdgcn_exp2f(acc[2]);
                    float e3 = __builtin_amdgcn_exp2f(acc[3]);
                    lsum[g] += (e0 + e1) + (e2 + e3);
                    pb[gl][t >> 1].u[t & 1] = pack4bf(e0, e1, e2, e3);
                }
            }
            // PV: O^T[d][q] += Vt_perm (A) * P^T-regs (B)
            #pragma unroll
            for (int n = 0; n < 4; n++) {
                bf16x8 va0 = *(const bf16x8*)&lv[n * 16 + m][quad * 8];
                bf16x8 va1 = *(const bf16x8*)&lv[n * 16 + m][32 + quad * 8];
                #pragma unroll
                for (int gl = 0; gl < 2; gl++) {
                    const int g = gp * 2 + gl;
                    o[g][n] = MFMA(va0, pb[gl][0].v, o[g][n]);
                    o[g][n] = MFMA(va1, pb[gl][1].v, o[g][n]);
                }
            }
        }
    }

    // ---- epilogue: l reduce, O^T regs -> A-fragments, fused @ Wo_perm + bo ----
    #pragma unroll
    for (int g = 0; g < 4; g++) {
        lsum[g] += __shfl_xor(lsum[g], 16);
        lsum[g] += __shfl_xor(lsum[g], 32);
    }

    bf16x8 wf[4][2];
    #pragma unroll
    for (int et = 0; et < 4; et++) {
        wf[et][0] = *(const bf16x8*)(wob + (size_t)(et * 16 + m) * 64 + quad * 8);
        wf[et][1] = *(const bf16x8*)(wob + (size_t)(et * 16 + m) * 64 + 32 + quad * 8);
    }
    float biasr[4];
    #pragma unroll
    for (int et = 0; et < 4; et++) biasr[et] = bo[et * 16 + m];

    #pragma unroll
    for (int g = 0; g < 4; g++) {
        const float inv = 1.f / lsum[g];
        frag_u af0, af1;
        af0.u[0] = pack4bf(o[g][0][0] * inv, o[g][0][1] * inv, o[g][0][2] * inv, o[g][0][3] * inv);
        af0.u[1] = pack4bf(o[g][1][0] * inv, o[g][1][1] * inv, o[g][1][2] * inv, o[g][1][3] * inv);
        af1.u[0] = pack4bf(o[g][2][0] * inv, o[g][2][1] * inv, o[g][2][2] * inv, o[g][2][3] * inv);
        af1.u[1] = pack4bf(o[g][3][0] * inv, o[g][3][1] * inv, o[g][3][2] * inv, o[g][3][3] * inv);
        #pragma unroll
        for (int et = 0; et < 4; et++) {
            f32x4 acc = {0.f, 0.f, 0.f, 0.f};
            acc = MFMA(af0.v, wf[et][0], acc);
            acc = MFMA(af1.v, wf[et][1], acc);
            #pragma unroll
            for (int r = 0; r < 4; r++) {
                size_t row = (size_t)bh * S + q0 + g * 16 + quad * 4 + r;
                out[row * 64 + et * 16 + m] = acc[r] + biasr[et];
            }
        }
    }
}

// ---------------------------------------------------------------------------
extern "C" void kernel_launch(void* const* d_in, const int* in_sizes, int n_in,
                              void* d_out, int out_size, void* d_ws, size_t ws_size,
                              hipStream_t stream) {
    const float* x  = (const float*)d_in[0];
    const float* Wq = (const float*)d_in[1];
    const float* bq = (const float*)d_in[2];
    const float* Wk = (const float*)d_in[3];
    const float* bk = (const float*)d_in[4];
    const float* Wv = (const float*)d_in[5];
    const float* bv = (const float*)d_in[6];
    const float* Wo = (const float*)d_in[7];
    const float* bo = (const float*)d_in[8];
    float* out = (float*)d_out;

    __bf16* gq  = (__bf16*)d_ws;
    __bf16* gk  = gq + NE;
    __bf16* gvt = gk + NE;
    __bf16* wob = gvt + NE;

    wo_conv<<<4, 256, 0, stream>>>(Wo, wob);
    proj_qkv<<<1536, 256, 0, stream>>>(x, Wq, bq, Wk, bk, Wv, bv, gq, gk, gvt);
    attn<<<dim3(192, 4), 256, 0, stream>>>(gq, gk, gvt, wob, bo, out);
}